// Round 3
// baseline (217.422 us; speedup 1.0000x reference)
//
#include <hip/hip_runtime.h>
#include <math.h>

#define BB 16
#define QQ 900
#define CC 91
#define TT 100
#define BT (BB * TT)        // 1600
#define NTHREADS 256
#define TILE 15             // query rows per cost block (900 % 15 == 0)
#define NBLK_PER_IMG (QQ / TILE)   // 60
#define NSLOT 15            // ceil(900/64) row slots per lane
#define WSCOLS 128          // u64 workspace slots per image
#define PENDK 8             // pending-buffer slots (R2 verified <=8 concurrent)

__device__ __forceinline__ unsigned ordkey(float f) {
    unsigned u = __float_as_uint(f);
    return (u & 0x80000000u) ? ~u : (u | 0x80000000u);
}

__device__ __forceinline__ unsigned long long u64min(unsigned long long a, unsigned long long b) {
    return a < b ? a : b;
}
__device__ __forceinline__ unsigned long long u64max(unsigned long long a, unsigned long long b) {
    return a > b ? a : b;
}

// pack (key,row,col) -> u64; lexicographic == numpy flat-index argmin order
__device__ __forceinline__ unsigned long long packkrc(unsigned key, int row, int col) {
    return ((unsigned long long)key << 21) | ((unsigned long long)row << 11) | (unsigned)col;
}

__device__ __forceinline__ unsigned long long rdlane64(unsigned long long v, int l) {
    unsigned lo = (unsigned)__builtin_amdgcn_readlane((int)(unsigned)v, l);
    unsigned hi = (unsigned)__builtin_amdgcn_readlane((int)(unsigned)(v >> 32), l);
    return ((unsigned long long)hi << 32) | lo;
}

// ---------------------------------------------------------------------------
// Kernel 1: cost[b,q,j], tiled 15 rows/block. AoS float4 target staging
// (1 ds_read_b128/entry instead of 4 ds_read_b32), nontemporal cost stores
// (no L2 pollution / write-allocate for the 92 MB stream). Column minima
// (cols 0..99) accumulate in a register and atomicMin into the workspace.
// Numerics: EXACT expression tree of the verified kernel.
// ---------------------------------------------------------------------------
__global__ __launch_bounds__(NTHREADS) void cost_kernel(
    const float* __restrict__ logits,
    const float* __restrict__ pred,
    const int*   __restrict__ tlab,
    const float* __restrict__ tbox,
    float*       __restrict__ cost,
    unsigned long long* __restrict__ colmin)
{
    const int b  = blockIdx.x / NBLK_PER_IMG;
    const int tb = blockIdx.x % NBLK_PER_IMG;
    const int r0 = tb * TILE;                 // first query row of this tile

    __shared__ float4 s_t[BT];                // 25.6 KB, AoS
    __shared__ int    s_lab[BT];              // 6.4 KB
    __shared__ float  s_sig[TILE][CC];        // 5.46 KB
    __shared__ float  s_row[TILE][8];         // px,py,pz,pw,x0,y0,x1,y1

    for (int j = threadIdx.x; j < BT; j += NTHREADS) {
        s_t[j] = *(const float4*)(tbox + (size_t)j * 4);
        s_lab[j] = tlab[j];
    }
    for (int u = threadIdx.x; u < TILE * CC; u += NTHREADS) {
        int r = u / CC, c = u % CC;
        float x = logits[((size_t)(b * QQ + r0 + r)) * CC + c];
        s_sig[r][c] = 1.0f / (1.0f + expf(-x));
    }
    if (threadIdx.x < TILE) {
        int r = threadIdx.x;
        const float4 p = *(const float4*)(pred + ((size_t)(b * QQ + r0 + r)) * 4);
        s_row[r][0] = p.x; s_row[r][1] = p.y; s_row[r][2] = p.z; s_row[r][3] = p.w;
        s_row[r][4] = p.x - 0.5f * p.z;
        s_row[r][5] = p.y - 0.5f * p.w;
        s_row[r][6] = p.x + 0.5f * p.z;
        s_row[r][7] = p.y + 0.5f * p.w;
    }
    __syncthreads();

    unsigned long long bestc = ~0ULL;   // column-min for col==threadIdx.x (<100)

    for (int r = 0; r < TILE; ++r) {
        const float px  = s_row[r][0], py  = s_row[r][1], pz  = s_row[r][2], pw  = s_row[r][3];
        const float p_x0 = s_row[r][4], p_y0 = s_row[r][5], p_x1 = s_row[r][6], p_y1 = s_row[r][7];
        const float area1 = (p_x1 - p_x0) * (p_y1 - p_y0);
        float* crow = cost + ((size_t)(b * QQ + r0 + r)) * BT;

        for (int j = threadIdx.x; j < BT; j += NTHREADS) {
            float4 t = s_t[j];
            float cclass = -s_sig[r][s_lab[j]];
            float cbbox = ((fabsf(px - t.x) + fabsf(py - t.y)) + fabsf(pz - t.z)) + fabsf(pw - t.w);

            float t_x0 = t.x - 0.5f * t.z, t_y0 = t.y - 0.5f * t.w;
            float t_x1 = t.x + 0.5f * t.z, t_y1 = t.y + 0.5f * t.w;
            float area2 = (t_x1 - t_x0) * (t_y1 - t_y0);

            float ltx = fmaxf(p_x0, t_x0), lty = fmaxf(p_y0, t_y0);
            float rbx = fminf(p_x1, t_x1), rby = fminf(p_y1, t_y1);
            float iw = fmaxf(rbx - ltx, 0.0f), ih = fmaxf(rby - lty, 0.0f);
            float inter = iw * ih;
            float uni = (area1 + area2) - inter;
            float iou = inter / uni;

            float ex0 = fminf(p_x0, t_x0), ey0 = fminf(p_y0, t_y0);
            float ex1 = fmaxf(p_x1, t_x1), ey1 = fmaxf(p_y1, t_y1);
            float ew = fmaxf(ex1 - ex0, 0.0f), eh = fmaxf(ey1 - ey0, 0.0f);
            float ae = ew * eh;
            float giou = iou - (ae - uni) / ae;

            float v = (cbbox + cclass) + (-giou);
            __builtin_nontemporal_store(v, &crow[j]);
            if (j < TT) bestc = u64min(bestc, packkrc(ordkey(v), r0 + r, j));
        }
    }

    if (threadIdx.x < TT)
        atomicMin(colmin + (size_t)b * WSCOLS + threadIdx.x, bestc);
}

// ---------------------------------------------------------------------------
// Kernel 2: greedy matcher = sorted lazy-deletion queue with BULK pops.
// Sort the 128 (padded) packed column minima once; then, per round, ALL
// lanes validate their sorted entries in parallel (LDS dead[] + first-rank
// dup table), one ballot finds the first "event" rank k, and ranks [cur,k)
// are matched in bulk (parallel stores + dead marks). Events (stale entry
// -> column rescan, or pending-pop) are rare (~10/image), so the serial
// loop runs ~15 rounds instead of 100+. Pop order is bit-identical to the
// reference flat-scan argmin (full u64 (key,row,col) lexicographic).
// ---------------------------------------------------------------------------
__global__ __launch_bounds__(64, 1) void greedy_kernel(
    const float* __restrict__ cost,
    const unsigned long long* __restrict__ colmin,
    float*       __restrict__ rows_out,
    float*       __restrict__ cols_out)
{
    const int b = blockIdx.x;
    const int lane = threadIdx.x;
    const float* cb = cost + (size_t)b * QQ * BT;

    __shared__ unsigned s_first[1024];     // min-rank per row (dup detect)
    __shared__ unsigned s_dead32[256];     // 1024 B of row-dead flags
    unsigned char* s_dead = (unsigned char*)s_dead32;

    #pragma unroll
    for (int kk = 0; kk < 4; ++kk) s_dead32[lane + kk * 64] = 0u;

    // ---- load 100 column minima; pad to 128 with ~0 ----
    unsigned long long va = colmin[(size_t)b * WSCOLS + lane];              // rank = lane
    unsigned long long vb = (lane < TT - 64)
                          ? colmin[(size_t)b * WSCOLS + 64 + lane] : ~0ULL; // rank = 64+lane

    // ---- bitonic sort, 128 elements across 64 lanes x 2 regs, ascending ----
    #pragma unroll
    for (int k = 2; k <= 128; k <<= 1) {
        #pragma unroll
        for (int j = k >> 1; j > 0; j >>= 1) {
            if (j == 64) {
                unsigned long long lo = u64min(va, vb);
                unsigned long long hi = va ^ vb ^ lo;
                va = lo; vb = hi;
            } else {
                unsigned long long pa = __shfl_xor(va, j, 64);
                bool ta = ((lane & j) == 0) == ((lane & k) == 0);
                va = ta ? u64min(va, pa) : u64max(va, pa);
                unsigned long long pb = __shfl_xor(vb, j, 64);
                int ib = lane + 64;
                bool tb_ = ((ib & j) == 0) == ((ib & k) == 0);
                vb = tb_ ? u64min(vb, pb) : u64max(vb, pb);
            }
        }
    }

    const int rA = (int)((va >> 11) & 0x3FF);   // static per-lane entry fields
    const int cA = (int)(va & 0x7FF);
    const int rB = (int)((vb >> 11) & 0x3FF);
    const int cB = (int)(vb & 0x7FF);

    unsigned long long pend[PENDK];
    #pragma unroll
    for (int t = 0; t < PENDK; ++t) pend[t] = ~0ULL;
    unsigned long long pmin = ~0ULL;

    int cur = 0;    // next unconsumed sorted rank (wave-uniform)
    int m = 0;      // matches emitted

    while (m < TT) {
        __asm__ volatile("s_waitcnt lgkmcnt(0)" ::: "memory");

        // reset first-rank table
        #pragma unroll
        for (int kk = 0; kk < 16; ++kk) s_first[lane + kk * 64] = 0xFFFFFFFFu;

        bool dA = s_dead[rA] != 0;
        bool dB = s_dead[rB] != 0;
        __asm__ volatile("s_waitcnt lgkmcnt(0)" ::: "memory");

        bool inA = (lane >= cur) && !dA;
        bool inB = ((64 + lane) >= cur) && !dB;
        if (inA) atomicMin(&s_first[rA], (unsigned)lane);
        if (inB) atomicMin(&s_first[rB], (unsigned)(64 + lane));
        __asm__ volatile("s_waitcnt lgkmcnt(0)" ::: "memory");

        bool dupA = inA && (s_first[rA] < (unsigned)lane);
        bool dupB = inB && (s_first[rB] < (unsigned)(64 + lane));

        // event = dead row, duplicated row in prefix, or pending interleave
        bool evA = (lane >= cur)        && (dA || dupA || (pmin < va));
        bool evB = ((64 + lane) >= cur) && (dB || dupB || (pmin < vb));
        unsigned long long mA = __ballot(evA);
        unsigned long long mB = __ballot(evB);
        int k = mA ? (int)__ffsll(mA) - 1
              : (mB ? 64 + (int)__ffsll(mB) - 1 : 128);

        int n = k - cur;
        if (n > TT - m) n = TT - m;   // never match into sentinel region

        if (n > 0) {
            // ---- bulk match ranks [cur, cur+n): all valid, rows unique ----
            int iA = lane - cur;
            if (iA >= 0 && iA < n) {
                rows_out[b * TT + m + iA] = (float)rA;
                cols_out[b * TT + m + iA] = (float)cA;
                s_dead[rA] = 1;
            }
            int iB = 64 + lane - cur;
            if (iB >= 0 && iB < n) {
                rows_out[b * TT + m + iB] = (float)rB;
                cols_out[b * TT + m + iB] = (float)cB;
                s_dead[rB] = 1;
            }
            m += n;
            cur += n;
            if (m >= TT) break;
        }

        // ---- single event at rank cur ----
        unsigned long long ecur = (cur < 64) ? rdlane64(va, cur)
                                : (cur < 128) ? rdlane64(vb, cur - 64) : ~0ULL;
        __asm__ volatile("s_waitcnt lgkmcnt(0)" ::: "memory");

        if (pmin < ecur) {
            // pop pending entry e
            unsigned long long e = pmin;
            bool removed = false;
            #pragma unroll
            for (int t = 0; t < PENDK; ++t)
                if (!removed && pend[t] == e) { pend[t] = ~0ULL; removed = true; }
            pmin = ~0ULL;
            #pragma unroll
            for (int t = 0; t < PENDK; ++t) pmin = u64min(pmin, pend[t]);

            int re = (int)((e >> 11) & 0x3FF);
            int ce = (int)(e & 0x7FF);
            bool alive = (s_dead[re] == 0);   // uniform broadcast read
            if (alive) {
                if (lane == 0) {
                    rows_out[b * TT + m] = (float)re;
                    cols_out[b * TT + m] = (float)ce;
                    s_dead[re] = 1;
                }
                ++m;
            } else {
                // re-rescan column ce over alive rows
                unsigned long long best = ~0ULL;
                #pragma unroll
                for (int i = 0; i < NSLOT; ++i) {
                    int r = i * 64 + lane;
                    bool ok = (r < QQ) && (s_dead[r] == 0);
                    if (ok) {
                        float v = cb[(size_t)r * BT + ce];
                        best = u64min(best, packkrc(ordkey(v), r, ce));
                    }
                }
                #pragma unroll
                for (int off = 1; off < 64; off <<= 1)
                    best = u64min(best, __shfl_xor(best, off, 64));
                bool placed = false;
                #pragma unroll
                for (int t = 0; t < PENDK; ++t)
                    if (!placed && pend[t] == ~0ULL) { pend[t] = best; placed = true; }
                pmin = u64min(pmin, best);
            }
        } else {
            // sorted entry at cur is stale (its row is dead): rescan its column
            int cc = (int)(ecur & 0x7FF);
            unsigned long long best = ~0ULL;
            #pragma unroll
            for (int i = 0; i < NSLOT; ++i) {
                int r = i * 64 + lane;
                bool ok = (r < QQ) && (s_dead[r] == 0);
                if (ok) {
                    float v = cb[(size_t)r * BT + cc];
                    best = u64min(best, packkrc(ordkey(v), r, cc));
                }
            }
            #pragma unroll
            for (int off = 1; off < 64; off <<= 1)
                best = u64min(best, __shfl_xor(best, off, 64));
            bool placed = false;
            #pragma unroll
            for (int t = 0; t < PENDK; ++t)
                if (!placed && pend[t] == ~0ULL) { pend[t] = best; placed = true; }
            pmin = u64min(pmin, best);
            ++cur;   // rank consumed into pending
        }
    }
}

extern "C" void kernel_launch(void* const* d_in, const int* in_sizes, int n_in,
                              void* d_out, int out_size, void* d_ws, size_t ws_size,
                              hipStream_t stream) {
    const float* logits = (const float*)d_in[0];   // [16,900,91]
    const float* pred   = (const float*)d_in[1];   // [16,900,4]
    const int*   tlab   = (const int*)d_in[2];     // [16,100]
    const float* tbox   = (const float*)d_in[3];   // [16,100,4]

    float* out = (float*)d_out;
    float* cost = out;                              // 23,040,000
    float* rows = out + (size_t)BB * QQ * BT;       // 1600
    float* cols = rows + (size_t)BB * TT;           // 1600

    unsigned long long* colmin = (unsigned long long*)d_ws;   // 16*128*8 = 16 KB

    // 0xFF-fill == ~0ULL sentinels (graph-capture legal)
    hipMemsetAsync(d_ws, 0xFF, (size_t)BB * WSCOLS * sizeof(unsigned long long), stream);

    cost_kernel<<<BB * NBLK_PER_IMG, NTHREADS, 0, stream>>>(logits, pred, tlab, tbox, cost, colmin);
    greedy_kernel<<<BB, 64, 0, stream>>>(cost, colmin, rows, cols);
}